// Round 6
// baseline (636.306 us; speedup 1.0000x reference)
//
#include <hip/hip_runtime.h>
#include <stdint.h>

typedef unsigned long long u64;

static __device__ __forceinline__ int uread(int v) { return __builtin_amdgcn_readfirstlane(v); }
// force fp32 materialization (blocks fma-contraction / reassociation / load-sinking)
static __device__ __forceinline__ float fr(float x) { __asm__ volatile("" : "+v"(x)); return x; }

// BIT-FROZEN bn chain, split: si precomputed per channel (same op order => identical bits)
static __device__ __forceinline__ float bn_scale(float g, float v) {
    return fr(g * fr(1.0f / fr(sqrtf(fr(v + 1e-5f)))));
}
static __device__ __forceinline__ bool bn_neg_s(float x, float si, float b, float m) {
    float t1 = fr(x - m);
    float t2 = fr(t1 * si);
    float bn = fr(t2 + b);
    return bn < 0.0f;
}

// ---------------- fused weight packing (sign: x>=0 -> +1; bit=1 means -1), ONE dispatch ----------------

__device__ __forceinline__ void d_packw1(const float* __restrict__ w, float* __restrict__ ws, int id) {
    if (id >= 27 * 128) return;
    int co = id & 127, j = id >> 7;
    ws[j * 128 + co] = (w[co * 27 + j] < 0.f) ? -1.f : 1.f;
}

// conv weights (COUT,CIN,3,3) -> bits [tap][word][COUT]; wave per (co,wrd), lane = channel-in-word.
__device__ __forceinline__ void d_pack_conv(const float* __restrict__ w, u64* __restrict__ wb,
                                            int CINW, int COUT, int wv, int lane) {
    int wrd = wv % CINW, co = wv / CINW;
    int CIN = CINW * 64;
    const float* p = w + ((size_t)co * CIN + (size_t)wrd * 64 + lane) * 9;
    float f[9];
#pragma unroll
    for (int t = 0; t < 9; ++t) f[t] = p[t];
#pragma unroll
    for (int t = 0; t < 9; ++t) {
        u64 bits = __ballot(f[t] < 0.f);
        if (lane == 0) wb[(size_t)(t * CINW + wrd) * COUT + co] = bits;
    }
}

__device__ __forceinline__ void d_packw7(const float* __restrict__ w, u64* __restrict__ wb, int wv, int lane) {
    int cw = wv & 7, o = wv >> 3;
    const float* p = w + (size_t)o * 8192 + (size_t)(cw * 64 + lane) * 16;
    float f[16];
#pragma unroll
    for (int i = 0; i < 16; i += 4) {
        float4 q = *(const float4*)(p + i);
        f[i] = q.x; f[i + 1] = q.y; f[i + 2] = q.z; f[i + 3] = q.w;
    }
#pragma unroll
    for (int pixel = 0; pixel < 16; ++pixel) {
        u64 bits = __ballot(f[pixel] < 0.f);
        if (lane == 0) wb[(size_t)(pixel * 8 + cw) * 1024 + o] = bits;
    }
}

__device__ __forceinline__ void d_packw8(const float* __restrict__ w, u64* __restrict__ wb, int wv, int lane) {
    int k = wv & 15, o = wv >> 4;
    float f = w[(size_t)o * 1024 + k * 64 + lane];
    u64 bits = __ballot(f < 0.f);
    if (lane == 0) wb[(size_t)k * 1024 + o] = bits;
}

__device__ __forceinline__ void d_packw9(const float* __restrict__ w, u64* __restrict__ wb, int wv, int lane) {
    if (wv >= 160) return;
    int k = wv & 15, o = wv >> 4;
    float f = w[(size_t)o * 1024 + k * 64 + lane];
    u64 bits = __ballot(f < 0.f);
    if (lane == 0) wb[k * 16 + o] = bits;
}

// block ranges: 14 | 64 | 128 | 256 | 512 | 1024 | 2048 | 4096 | 40  = 8182 blocks
__global__ __launch_bounds__(256) void pack_all_kernel(
    const float* __restrict__ w1, float* __restrict__ w1s,
    const float* __restrict__ w2, u64* __restrict__ w2p,
    const float* __restrict__ w3, u64* __restrict__ w3p,
    const float* __restrict__ w4, u64* __restrict__ w4p,
    const float* __restrict__ w5, u64* __restrict__ w5p,
    const float* __restrict__ w6, u64* __restrict__ w6p,
    const float* __restrict__ w7, u64* __restrict__ w7p,
    const float* __restrict__ w8, u64* __restrict__ w8p,
    const float* __restrict__ w9, u64* __restrict__ w9p)
{
    int b = blockIdx.x;
    int lane = threadIdx.x & 63;
    int wq = threadIdx.x >> 6;
    if (b < 14) { d_packw1(w1, w1s, b * 256 + threadIdx.x); return; } b -= 14;
    if (b < 64) { d_pack_conv(w2, w2p, 2, 128, b * 4 + wq, lane); return; } b -= 64;
    if (b < 128) { d_pack_conv(w3, w3p, 2, 256, b * 4 + wq, lane); return; } b -= 128;
    if (b < 256) { d_pack_conv(w4, w4p, 4, 256, b * 4 + wq, lane); return; } b -= 256;
    if (b < 512) { d_pack_conv(w5, w5p, 4, 512, b * 4 + wq, lane); return; } b -= 512;
    if (b < 1024) { d_pack_conv(w6, w6p, 8, 512, b * 4 + wq, lane); return; } b -= 1024;
    if (b < 2048) { d_packw7(w7, w7p, b * 4 + wq, lane); return; } b -= 2048;
    if (b < 4096) { d_packw8(w8, w8p, b * 4 + wq, lane); return; } b -= 4096;
    d_packw9(w9, w9p, b * 4 + wq, lane);
}

// ---------------- conv1: fp32, Eigen/XLA-CPU order (BIT-FROZEN chain), register-resident ----------------
__global__ __launch_bounds__(256, 4) void conv1_kernel(
    const float* __restrict__ x, const float* __restrict__ w1s,
    const float* __restrict__ g, const float* __restrict__ bb,
    const float* __restrict__ m, const float* __restrict__ v,
    u64* __restrict__ out, int N)
{
    int lane = threadIdx.x & 63;
    int rid = uread(blockIdx.x * 4 + (threadIdx.x >> 6));
    if (rid >= N * 32) return;
    int n = rid >> 5, y = rid & 31;
    const float* xb = x + (size_t)n * 3072;
    const bool rv0 = (y > 0), rv2 = (y < 31);
    const int y0 = rv0 ? y - 1 : 0, y2 = rv2 ? y + 1 : 31;

    int co0 = lane, co1 = 64 + lane;
    float w0[27], w1[27];
#pragma unroll
    for (int j = 0; j < 27; ++j) {
        w0[j] = fr(w1s[j * 128 + co0]);
        w1[j] = fr(w1s[j * 128 + co1]);
    }
    float b0 = bb[co0], m0 = m[co0];
    float b1 = bb[co1], m1 = m[co1];
    float si0 = bn_scale(g[co0], v[co0]);
    float si1 = bn_scale(g[co1], v[co1]);

    float cm[9], cc[9], cn[9];
#pragma unroll
    for (int t = 0; t < 9; ++t) cm[t] = 0.f;

    auto ldcol = [&](float* c, int xs) {
#pragma unroll
        for (int ci = 0; ci < 3; ++ci) {
            float a0 = xb[ci * 1024 + y0 * 32 + xs];
            float a1 = xb[ci * 1024 + y  * 32 + xs];
            float a2 = xb[ci * 1024 + y2 * 32 + xs];
            c[0 + ci] = fr(rv0 ? a0 : 0.f);
            c[3 + ci] = fr(a1);
            c[6 + ci] = fr(rv2 ? a2 : 0.f);
        }
    };
    ldcol(cc, 0);

    u64* orow = out + (((size_t)n * 32 + y) * 32) * 2;

    for (int xx = 0; xx < 32; ++xx) {
        if (xx < 31) ldcol(cn, xx + 1);
        else {
#pragma unroll
            for (int t = 0; t < 9; ++t) cn[t] = 0.f;
        }
        float a0 = 0.f, a1 = 0.f;
#pragma unroll
        for (int ky = 0; ky < 3; ++ky) {
#pragma unroll
            for (int ci = 0; ci < 3; ++ci) a0 = fmaf(w0[ci * 9 + ky * 3 + 0], cm[ky * 3 + ci], a0);
#pragma unroll
            for (int ci = 0; ci < 3; ++ci) a0 = fmaf(w0[ci * 9 + ky * 3 + 1], cc[ky * 3 + ci], a0);
#pragma unroll
            for (int ci = 0; ci < 3; ++ci) a0 = fmaf(w0[ci * 9 + ky * 3 + 2], cn[ky * 3 + ci], a0);
        }
#pragma unroll
        for (int ky = 0; ky < 3; ++ky) {
#pragma unroll
            for (int ci = 0; ci < 3; ++ci) a1 = fmaf(w1[ci * 9 + ky * 3 + 0], cm[ky * 3 + ci], a1);
#pragma unroll
            for (int ci = 0; ci < 3; ++ci) a1 = fmaf(w1[ci * 9 + ky * 3 + 1], cc[ky * 3 + ci], a1);
#pragma unroll
            for (int ci = 0; ci < 3; ++ci) a1 = fmaf(w1[ci * 9 + ky * 3 + 2], cn[ky * 3 + ci], a1);
        }
        u64 bits0 = __ballot(bn_neg_s(a0, si0, b0, m0));
        u64 bits1 = __ballot(bn_neg_s(a1, si1, b1, m1));
        if (lane == 0) {
            ulonglong2 st; st.x = bits0; st.y = bits1;
            *(ulonglong2*)(orow + xx * 2) = st;
        }
#pragma unroll
        for (int t = 0; t < 9; ++t) { cm[t] = cc[t]; cc[t] = cn[t]; }
    }
}

// ---------------- binary conv, LDS-staged (XNOR-popcount), fp32 bit-exact epilogue ----------------
// R5: K-chunk path now single-word granularity (wc[9]=18 VGPR, win u64[PR][PR]=16) -- real
// demand ~80-90 VGPR vs MINW=4's 128 cap (pair-chunk demanded ~160 -> 96 MB scratch/dispatch).
// NOTE: counter CSV VGPR_Count is in 2-reg granules (R1-R5 cross-check). W2==1 path untouched.
template<int WORDS, int COW, bool POOL, bool HAS_BIAS, int H, int YS, int NWAVES, int MINW>
__global__ __launch_bounds__(NWAVES * 64, MINW) void binconv_lds(
    const u64* __restrict__ a, const u64* __restrict__ wb,
    const float* __restrict__ g, const float* __restrict__ bb,
    const float* __restrict__ m, const float* __restrict__ v,
    const float* __restrict__ bias, u64* __restrict__ out, int N)
{
    const int W = H;
    const int OH = POOL ? H / 2 : H, OW = POOL ? W / 2 : W;
    const int COUT = COW * 64;
    const int OROWS = OH / YS;
    const int RMAX = POOL ? OROWS * 2 + 2 : OROWS + 2;
    const int PR = POOL ? 4 : 3;
    const int NW = POOL ? 4 : 1;
    const int W2 = WORDS / 2;
    const int S = POOL ? 2 : 1;          // x stride between outputs
    const int NBC = 9 * WORDS * 64;      // valid bits per subwindow, interior
    const int GPX = (OW <= 4) ? OW : ((NW == 4) ? 4 : OW);   // pixels per acc-group
    const int NG = OW / GPX;

    __shared__ alignas(16) u64 tile[RMAX * W * WORDS];

    int blk = blockIdx.x;
    int ys = blk % YS, n = blk / YS;
    int oy0 = ys * OROWS;
    int iy0 = (POOL ? oy0 * 2 - 1 : oy0 - 1); if (iy0 < 0) iy0 = 0;
    int iy1 = (POOL ? (oy0 + OROWS - 1) * 2 + 2 : oy0 + OROWS); if (iy1 > H - 1) iy1 = H - 1;
    int R = iy1 - iy0 + 1;
    {
        const u64* src = a + ((size_t)(n * H + iy0) * W) * WORDS;
        int tot = R * W * WORDS;
        for (int i = threadIdx.x; i < tot; i += NWAVES * 64) tile[i] = src[i];
    }
    __syncthreads();

    int lane = threadIdx.x & 63;
    int wv = uread((int)(threadIdx.x >> 6));

    int cw0, r0, r1;
    if (COW >= NWAVES) { cw0 = wv; r0 = 0; r1 = OROWS; }
    else { cw0 = wv % COW; int chunk = OROWS * COW / NWAVES; r0 = (wv / COW) * chunk; r1 = r0 + chunk; }

    const ulonglong2* t2 = (const ulonglong2*)tile;

    for (int cw = cw0; cw < COW; cw += NWAVES) {
        int co = cw * 64 + lane;
        float bc = bb[co], mc = m[co];
        float sic = bn_scale(g[co], v[co]);
        float bi = HAS_BIAS ? bias[co] : 0.f;

        auto store_px = [&](int oy, int ox, int best) {
            float tv = (float)best;
            if (HAS_BIAS) tv = fr(tv + bi);
            u64 bits = __ballot(bn_neg_s(tv, sic, bc, mc));
            if (lane == 0) out[((size_t)(n * OH + oy) * OW + ox) * COW + cw] = bits;
        };

        if constexpr (W2 == 1) {
            u64 wgt[18];
#pragma unroll
            for (int t = 0; t < 18; ++t) wgt[t] = wb[(size_t)t * COUT + co];

            // general (border-capable) path — BIT-FROZEN
            auto px_general = [&](int oy, int ox) {
                int y0 = (POOL ? oy * 2 : oy) - 1;
                bool rv[PR];
#pragma unroll
                for (int p = 0; p < PR; ++p) rv[p] = ((unsigned)(y0 + p) < (unsigned)H);
                int x0 = (POOL ? ox * 2 : ox) - 1;
                bool cv[PR];
#pragma unroll
                for (int q = 0; q < PR; ++q) cv[q] = ((unsigned)(x0 + q) < (unsigned)W);

                int acc[NW], nb[NW];
#pragma unroll
                for (int i = 0; i < NW; ++i) { acc[i] = 0; nb[i] = 0; }
#pragma unroll
                for (int sy = 0; sy < (POOL ? 2 : 1); ++sy)
#pragma unroll
                for (int sx = 0; sx < (POOL ? 2 : 1); ++sx)
#pragma unroll
                for (int ky = 0; ky < 3; ++ky)
#pragma unroll
                for (int kx = 0; kx < 3; ++kx)
                    if (rv[sy + ky] && cv[sx + kx]) nb[POOL ? sy * 2 + sx : 0] += WORDS * 64;

                ulonglong2 pt[PR][PR];
#pragma unroll
                for (int p = 0; p < PR; ++p) if (rv[p]) {
                    int lrow = y0 + p - iy0;
#pragma unroll
                    for (int q = 0; q < PR; ++q) if (cv[q])
                        pt[p][q] = t2[(lrow * W + (x0 + q))];
                }
#pragma unroll
                for (int sy = 0; sy < (POOL ? 2 : 1); ++sy)
#pragma unroll
                for (int sx = 0; sx < (POOL ? 2 : 1); ++sx)
#pragma unroll
                for (int ky = 0; ky < 3; ++ky)
#pragma unroll
                for (int kx = 0; kx < 3; ++kx)
                    if (rv[sy + ky] && cv[sx + kx]) {
                        ulonglong2 q = pt[sy + ky][sx + kx];
                        int wi = POOL ? sy * 2 + sx : 0;
                        acc[wi] += __popcll(q.x ^ wgt[(ky * 3 + kx) * 2])
                                 + __popcll(q.y ^ wgt[(ky * 3 + kx) * 2 + 1]);
                    }
                int best = 0;
#pragma unroll
                for (int i = 0; i < NW; ++i) {
                    int dot = nb[i] - 2 * acc[i];
                    best = (i == 0) ? dot : max(best, dot);
                }
                store_px(oy, ox, best);
            };

            for (int oy = oy0 + r0; oy < oy0 + r1; ++oy) {
                int y0 = (POOL ? oy * 2 : oy) - 1;
                if (y0 < 0 || y0 + PR > H) {           // border row: full general path
                    for (int ox = 0; ox < OW; ++ox) px_general(oy, ox);
                    continue;
                }
                int base = y0 - iy0;                   // top tile row of the window (in-tile, valid)
                px_general(oy, 0);
                for (int ox = 1; ox < OW - 1; ++ox) {
                    int x0 = S * ox - 1;
                    int acc[NW];
#pragma unroll
                    for (int i = 0; i < NW; ++i) acc[i] = 0;
                    ulonglong2 win[PR][PR];
#pragma unroll
                    for (int p = 0; p < PR; ++p) {
                        const ulonglong2* rp = t2 + (base + p) * W + x0;
#pragma unroll
                        for (int q = 0; q < PR; ++q) win[p][q] = rp[q];
                    }
#pragma unroll
                    for (int sy = 0; sy < (POOL ? 2 : 1); ++sy)
#pragma unroll
                    for (int sx = 0; sx < (POOL ? 2 : 1); ++sx)
#pragma unroll
                    for (int ky = 0; ky < 3; ++ky)
#pragma unroll
                    for (int kx = 0; kx < 3; ++kx) {
                        ulonglong2 q = win[sy + ky][sx + kx];
                        int wi = POOL ? sy * 2 + sx : 0;
                        acc[wi] += __popcll(q.x ^ wgt[(ky * 3 + kx) * 2])
                                 + __popcll(q.y ^ wgt[(ky * 3 + kx) * 2 + 1]);
                    }
                    int best = 0;
#pragma unroll
                    for (int i = 0; i < NW; ++i) {
                        int dot = NBC - 2 * acc[i];
                        best = (i == 0) ? dot : max(best, dot);
                    }
                    store_px(oy, ox, best);
                }
                px_general(oy, OW - 1);
            }
        } else {
            // ---- K-chunked path (WORDS >= 4): single-word chunks, wc[9] + u64 win ----
            for (int oy = oy0 + r0; oy < oy0 + r1; ++oy) {
                int y0r = (POOL ? oy * 2 : oy) - 1;
                bool rv[PR];
#pragma unroll
                for (int p = 0; p < PR; ++p) rv[p] = ((unsigned)(y0r + p) < (unsigned)H);
                int baseR = y0r - iy0;                 // only used where rv[p] true -> in-tile

#pragma unroll
                for (int gg = 0; gg < NG; ++gg) {
                    int acc[GPX][NW];
#pragma unroll
                    for (int i = 0; i < GPX; ++i)
#pragma unroll
                        for (int wi = 0; wi < NW; ++wi) acc[i][wi] = 0;

#pragma unroll 1
                    for (int w = 0; w < WORDS; ++w) {
                        u64 wc[9];
#pragma unroll
                        for (int t = 0; t < 9; ++t)
                            wc[t] = wb[(size_t)(t * WORDS + w) * COUT + co];
                        u64 win[PR][PR];
#pragma unroll
                        for (int i = 0; i < GPX; ++i) {
                            const int ox = gg * GPX + i;
                            const int x0 = S * ox - 1;
                            if (i == 0) {
#pragma unroll
                                for (int q = 0; q < PR; ++q) {
                                    const int x = x0 + q;
                                    if (x >= 0 && x < W) {
#pragma unroll
                                        for (int p = 0; p < PR; ++p)
                                            if (rv[p]) win[p][q] = tile[((baseR + p) * W + x) * WORDS + w];
                                    }
                                }
                            } else {
#pragma unroll
                                for (int p = 0; p < PR; ++p)
#pragma unroll
                                    for (int q = 0; q < PR - S; ++q) win[p][q] = win[p][q + S];
#pragma unroll
                                for (int s = 0; s < S; ++s) {
                                    const int x = x0 + PR - S + s;
                                    if (x >= 0 && x < W) {
#pragma unroll
                                        for (int p = 0; p < PR; ++p)
                                            if (rv[p]) win[p][PR - S + s] = tile[((baseR + p) * W + x) * WORDS + w];
                                    }
                                }
                            }
#pragma unroll
                            for (int sy = 0; sy < (POOL ? 2 : 1); ++sy)
#pragma unroll
                            for (int sx = 0; sx < (POOL ? 2 : 1); ++sx)
#pragma unroll
                            for (int ky = 0; ky < 3; ++ky)
#pragma unroll
                            for (int kx = 0; kx < 3; ++kx) {
                                const int xq = x0 + sx + kx;       // compile-time
                                if (xq >= 0 && xq < W) {
                                    if (rv[sy + ky]) {
                                        const int wi = POOL ? sy * 2 + sx : 0;
                                        acc[i][wi] += __popcll(win[sy + ky][sx + kx] ^ wc[ky * 3 + kx]);
                                    }
                                }
                            }
                        }
                    }

                    // epilogue: nb from (compile-time cv) x (runtime rv), pooled max, bn sign
#pragma unroll
                    for (int i = 0; i < GPX; ++i) {
                        const int ox = gg * GPX + i;
                        const int x0 = S * ox - 1;
                        int nb[NW];
#pragma unroll
                        for (int wi = 0; wi < NW; ++wi) nb[wi] = 0;
#pragma unroll
                        for (int sy = 0; sy < (POOL ? 2 : 1); ++sy)
#pragma unroll
                        for (int sx = 0; sx < (POOL ? 2 : 1); ++sx)
#pragma unroll
                        for (int ky = 0; ky < 3; ++ky)
#pragma unroll
                        for (int kx = 0; kx < 3; ++kx) {
                            const int xq = x0 + sx + kx;
                            if (xq >= 0 && xq < W) {
                                if (rv[sy + ky]) nb[POOL ? sy * 2 + sx : 0] += WORDS * 64;
                            }
                        }
                        int best = 0;
#pragma unroll
                        for (int wi = 0; wi < NW; ++wi) {
                            int dot = nb[wi] - 2 * acc[i][wi];
                            best = (wi == 0) ? dot : max(best, dot);
                        }
                        store_px(oy, ox, best);
                    }
                }
            }
        }
    }
}

// ---------------- binary FC, fp32 bit-exact epilogue (frozen) ----------------
template<int KW, int OWRD>
__global__ __launch_bounds__(256) void binfc_kernel(
    const u64* __restrict__ a, const u64* __restrict__ wb,
    const float* __restrict__ g, const float* __restrict__ bb,
    const float* __restrict__ m, const float* __restrict__ v,
    u64* __restrict__ out, int N)
{
    int lane = threadIdx.x & 63;
    int wid = uread(blockIdx.x * 4 + (threadIdx.x >> 6));
    if (wid >= N * OWRD) return;
    int ow = wid & (OWRD - 1), n = wid / OWRD;
    int o = ow * 64 + lane;
    const u64* ap = a + (size_t)n * KW;
    int acc = 0;
#pragma unroll 8
    for (int k = 0; k < KW; ++k)
        acc += __popcll(ap[k] ^ wb[(size_t)k * (OWRD * 64) + o]);
    float dotf = (float)(KW * 64 - 2 * acc);
    float si = bn_scale(g[o], v[o]);
    u64 bits = __ballot(bn_neg_s(dotf, si, bb[o], m[o]));
    if (lane == 0) out[(size_t)n * OWRD + ow] = bits;
}

// ---------------- fc9 + bn(affine=False) + log_softmax, fp32 output (frozen) ----------------
__global__ __launch_bounds__(64) void fc9_kernel(
    const u64* __restrict__ a, const u64* __restrict__ wb,
    const float* __restrict__ m, const float* __restrict__ v, float* __restrict__ out)
{
    int n = blockIdx.x, t = threadIdx.x;
    const u64* ap = a + (size_t)n * 16;
    float val = -1e30f;
    if (t < 10) {
        int acc = 0;
#pragma unroll
        for (int k = 0; k < 16; ++k) acc += __popcll(ap[k] ^ wb[k * 16 + t]);
        float dotf = (float)(1024 - 2 * acc);
        float inv = fr(1.0f / fr(sqrtf(fr(v[t] + 1e-5f))));
        float t1  = fr(dotf - m[t]);
        val = fr(t1 * inv);
    }
    float mx = val;
#pragma unroll
    for (int off = 32; off; off >>= 1) mx = fmaxf(mx, __shfl_xor(mx, off));
    float sh = fr(val - mx);
    double e = (t < 10) ? exp((double)sh) : 0.0;
    double sum = e;
#pragma unroll
    for (int off = 32; off; off >>= 1) sum += __shfl_xor(sum, off);
    if (t < 10) out[n * 10 + t] = (float)((double)sh - log(sum));
}

extern "C" void kernel_launch(void* const* d_in, const int* in_sizes, int n_in,
                              void* d_out, int out_size, void* d_ws, size_t ws_size,
                              hipStream_t stream) {
    // setup_inputs() dict order
    auto F = [&](int i) { return (const float*)d_in[i]; };
    const float* x  = F(0);
    const float* w1 = F(1);  const float* g1 = F(2);  const float* b1 = F(3);
    const float* m1 = F(4);  const float* v1 = F(5);
    const float* w2 = F(6);  const float* g2 = F(7);  const float* b2 = F(8);
    const float* m2 = F(9);  const float* v2 = F(10);
    const float* w3 = F(11); const float* g3 = F(12); const float* b3 = F(13);
    const float* m3 = F(14); const float* v3 = F(15);
    const float* w4 = F(16); const float* g4 = F(17); const float* b4 = F(18);
    const float* m4 = F(19); const float* v4 = F(20);
    const float* w5 = F(21); const float* g5 = F(22); const float* b5 = F(23);
    const float* m5 = F(24); const float* v5 = F(25);
    const float* w6 = F(26); const float* g6 = F(27); const float* b6 = F(28);
    const float* m6 = F(29); const float* v6 = F(30);
    const float* bias2 = F(31);
    const float* w7 = F(32); const float* m7 = F(33); const float* v7 = F(34);
    const float* g7 = F(35); const float* b7 = F(36);
    const float* w8 = F(37); const float* m8 = F(38); const float* v8 = F(39);
    const float* g8 = F(40); const float* b8 = F(41);
    const float* w9 = F(42); const float* m9 = F(43); const float* v9 = F(44);
    (void)in_sizes; (void)n_in; (void)ws_size;

    const int N = out_size / 10;
    u64* ws = (u64*)d_ws;
    size_t off = 0;
    auto carve = [&](size_t nwords) { u64* p = ws + off; off += nwords; return p; };
    float* w1s = (float*)carve(1728);
    u64* w2p = carve(2304);
    u64* w3p = carve(4608);
    u64* w4p = carve(9216);
    u64* w5p = carve(18432);
    u64* w6p = carve(36864);
    u64* w7p = carve(131072);
    u64* w8p = carve(16384);
    u64* w9p = carve(256);
    u64* a1 = carve((size_t)N * 32 * 32 * 2);
    u64* a2 = carve((size_t)N * 16 * 16 * 2);
    u64* a3 = carve((size_t)N * 16 * 16 * 4);
    u64* a4 = carve((size_t)N * 8 * 8 * 4);
    u64* a5 = carve((size_t)N * 8 * 8 * 8);
    u64* a6 = carve((size_t)N * 16 * 8);
    u64* f7 = carve((size_t)N * 16);
    u64* f8 = carve((size_t)N * 16);

    pack_all_kernel<<<8182, 256, 0, stream>>>(w1, w1s, w2, w2p, w3, w3p, w4, w4p,
                                              w5, w5p, w6, w6p, w7, w7p, w8, w8p, w9, w9p);

    conv1_kernel<<<(N * 32 + 3) / 4, 256, 0, stream>>>(x, w1s, g1, b1, m1, v1, a1, N);

    // binconv: conv2-5 at YS=8 (8 blocks/CU), conv6 at YS=4 with 8-wave blocks; MINW=4
    binconv_lds<2, 2, true, true, 32, 8, 4, 4><<<N * 8, 256, 0, stream>>>(
        a1, w2p, g2, b2, m2, v2, bias2, a2, N);
    binconv_lds<2, 4, false, false, 16, 8, 4, 4><<<N * 8, 256, 0, stream>>>(
        a2, w3p, g3, b3, m3, v3, nullptr, a3, N);
    binconv_lds<4, 4, true, false, 16, 8, 4, 4><<<N * 8, 256, 0, stream>>>(
        a3, w4p, g4, b4, m4, v4, nullptr, a4, N);
    binconv_lds<4, 8, false, false, 8, 8, 4, 4><<<N * 8, 256, 0, stream>>>(
        a4, w5p, g5, b5, m5, v5, nullptr, a5, N);
    binconv_lds<8, 8, true, false, 8, 4, 8, 4><<<N * 4, 512, 0, stream>>>(
        a5, w6p, g6, b6, m6, v6, nullptr, a6, N);

    binfc_kernel<128, 16><<<(N * 16 + 3) / 4, 256, 0, stream>>>(a6, w7p, g7, b7, m7, v7, f7, N);
    binfc_kernel<16, 16><<<(N * 16 + 3) / 4, 256, 0, stream>>>(f7, w8p, g8, b8, m8, v8, f8, N);

    fc9_kernel<<<N, 64, 0, stream>>>(f8, w9p, m9, v9, (float*)d_out);
}

// Round 7
// 578.491 us; speedup vs baseline: 1.0999x; 1.0999x over previous
//
#include <hip/hip_runtime.h>
#include <stdint.h>

typedef unsigned long long u64;

static __device__ __forceinline__ int uread(int v) { return __builtin_amdgcn_readfirstlane(v); }
// force fp32 materialization (blocks fma-contraction / reassociation / load-sinking)
static __device__ __forceinline__ float fr(float x) { __asm__ volatile("" : "+v"(x)); return x; }

// BIT-FROZEN bn chain, split: si precomputed per channel (same op order => identical bits)
static __device__ __forceinline__ float bn_scale(float g, float v) {
    return fr(g * fr(1.0f / fr(sqrtf(fr(v + 1e-5f)))));
}
static __device__ __forceinline__ bool bn_neg_s(float x, float si, float b, float m) {
    float t1 = fr(x - m);
    float t2 = fr(t1 * si);
    float bn = fr(t2 + b);
    return bn < 0.0f;
}

// ---------------- fused weight packing (sign: x>=0 -> +1; bit=1 means -1), ONE dispatch ----------------

__device__ __forceinline__ void d_packw1(const float* __restrict__ w, float* __restrict__ ws, int id) {
    if (id >= 27 * 128) return;
    int co = id & 127, j = id >> 7;
    ws[j * 128 + co] = (w[co * 27 + j] < 0.f) ? -1.f : 1.f;
}

// conv weights (COUT,CIN,3,3) -> bits [tap][word][COUT]; wave per (co,wrd), lane = channel-in-word.
__device__ __forceinline__ void d_pack_conv(const float* __restrict__ w, u64* __restrict__ wb,
                                            int CINW, int COUT, int wv, int lane) {
    int wrd = wv % CINW, co = wv / CINW;
    int CIN = CINW * 64;
    const float* p = w + ((size_t)co * CIN + (size_t)wrd * 64 + lane) * 9;
    float f[9];
#pragma unroll
    for (int t = 0; t < 9; ++t) f[t] = p[t];
#pragma unroll
    for (int t = 0; t < 9; ++t) {
        u64 bits = __ballot(f[t] < 0.f);
        if (lane == 0) wb[(size_t)(t * CINW + wrd) * COUT + co] = bits;
    }
}

__device__ __forceinline__ void d_packw7(const float* __restrict__ w, u64* __restrict__ wb, int wv, int lane) {
    int cw = wv & 7, o = wv >> 3;
    const float* p = w + (size_t)o * 8192 + (size_t)(cw * 64 + lane) * 16;
    float f[16];
#pragma unroll
    for (int i = 0; i < 16; i += 4) {
        float4 q = *(const float4*)(p + i);
        f[i] = q.x; f[i + 1] = q.y; f[i + 2] = q.z; f[i + 3] = q.w;
    }
#pragma unroll
    for (int pixel = 0; pixel < 16; ++pixel) {
        u64 bits = __ballot(f[pixel] < 0.f);
        if (lane == 0) wb[(size_t)(pixel * 8 + cw) * 1024 + o] = bits;
    }
}

__device__ __forceinline__ void d_packw8(const float* __restrict__ w, u64* __restrict__ wb, int wv, int lane) {
    int k = wv & 15, o = wv >> 4;
    float f = w[(size_t)o * 1024 + k * 64 + lane];
    u64 bits = __ballot(f < 0.f);
    if (lane == 0) wb[(size_t)k * 1024 + o] = bits;
}

__device__ __forceinline__ void d_packw9(const float* __restrict__ w, u64* __restrict__ wb, int wv, int lane) {
    if (wv >= 160) return;
    int k = wv & 15, o = wv >> 4;
    float f = w[(size_t)o * 1024 + k * 64 + lane];
    u64 bits = __ballot(f < 0.f);
    if (lane == 0) wb[k * 16 + o] = bits;
}

// block ranges: 14 | 64 | 128 | 256 | 512 | 1024 | 2048 | 4096 | 40  = 8182 blocks
__global__ __launch_bounds__(256) void pack_all_kernel(
    const float* __restrict__ w1, float* __restrict__ w1s,
    const float* __restrict__ w2, u64* __restrict__ w2p,
    const float* __restrict__ w3, u64* __restrict__ w3p,
    const float* __restrict__ w4, u64* __restrict__ w4p,
    const float* __restrict__ w5, u64* __restrict__ w5p,
    const float* __restrict__ w6, u64* __restrict__ w6p,
    const float* __restrict__ w7, u64* __restrict__ w7p,
    const float* __restrict__ w8, u64* __restrict__ w8p,
    const float* __restrict__ w9, u64* __restrict__ w9p)
{
    int b = blockIdx.x;
    int lane = threadIdx.x & 63;
    int wq = threadIdx.x >> 6;
    if (b < 14) { d_packw1(w1, w1s, b * 256 + threadIdx.x); return; } b -= 14;
    if (b < 64) { d_pack_conv(w2, w2p, 2, 128, b * 4 + wq, lane); return; } b -= 64;
    if (b < 128) { d_pack_conv(w3, w3p, 2, 256, b * 4 + wq, lane); return; } b -= 128;
    if (b < 256) { d_pack_conv(w4, w4p, 4, 256, b * 4 + wq, lane); return; } b -= 256;
    if (b < 512) { d_pack_conv(w5, w5p, 4, 512, b * 4 + wq, lane); return; } b -= 512;
    if (b < 1024) { d_pack_conv(w6, w6p, 8, 512, b * 4 + wq, lane); return; } b -= 1024;
    if (b < 2048) { d_packw7(w7, w7p, b * 4 + wq, lane); return; } b -= 2048;
    if (b < 4096) { d_packw8(w8, w8p, b * 4 + wq, lane); return; } b -= 4096;
    d_packw9(w9, w9p, b * 4 + wq, lane);
}

// ---------------- conv1: fp32, Eigen/XLA-CPU order (BIT-FROZEN chain), register-resident ----------------
__global__ __launch_bounds__(256, 4) void conv1_kernel(
    const float* __restrict__ x, const float* __restrict__ w1s,
    const float* __restrict__ g, const float* __restrict__ bb,
    const float* __restrict__ m, const float* __restrict__ v,
    u64* __restrict__ out, int N)
{
    int lane = threadIdx.x & 63;
    int rid = uread(blockIdx.x * 4 + (threadIdx.x >> 6));
    if (rid >= N * 32) return;
    int n = rid >> 5, y = rid & 31;
    const float* xb = x + (size_t)n * 3072;
    const bool rv0 = (y > 0), rv2 = (y < 31);
    const int y0 = rv0 ? y - 1 : 0, y2 = rv2 ? y + 1 : 31;

    int co0 = lane, co1 = 64 + lane;
    float w0[27], w1[27];
#pragma unroll
    for (int j = 0; j < 27; ++j) {
        w0[j] = fr(w1s[j * 128 + co0]);
        w1[j] = fr(w1s[j * 128 + co1]);
    }
    float b0 = bb[co0], m0 = m[co0];
    float b1 = bb[co1], m1 = m[co1];
    float si0 = bn_scale(g[co0], v[co0]);
    float si1 = bn_scale(g[co1], v[co1]);

    float cm[9], cc[9], cn[9];
#pragma unroll
    for (int t = 0; t < 9; ++t) cm[t] = 0.f;

    auto ldcol = [&](float* c, int xs) {
#pragma unroll
        for (int ci = 0; ci < 3; ++ci) {
            float a0 = xb[ci * 1024 + y0 * 32 + xs];
            float a1 = xb[ci * 1024 + y  * 32 + xs];
            float a2 = xb[ci * 1024 + y2 * 32 + xs];
            c[0 + ci] = fr(rv0 ? a0 : 0.f);
            c[3 + ci] = fr(a1);
            c[6 + ci] = fr(rv2 ? a2 : 0.f);
        }
    };
    ldcol(cc, 0);

    u64* orow = out + (((size_t)n * 32 + y) * 32) * 2;

    for (int xx = 0; xx < 32; ++xx) {
        if (xx < 31) ldcol(cn, xx + 1);
        else {
#pragma unroll
            for (int t = 0; t < 9; ++t) cn[t] = 0.f;
        }
        float a0 = 0.f, a1 = 0.f;
#pragma unroll
        for (int ky = 0; ky < 3; ++ky) {
#pragma unroll
            for (int ci = 0; ci < 3; ++ci) a0 = fmaf(w0[ci * 9 + ky * 3 + 0], cm[ky * 3 + ci], a0);
#pragma unroll
            for (int ci = 0; ci < 3; ++ci) a0 = fmaf(w0[ci * 9 + ky * 3 + 1], cc[ky * 3 + ci], a0);
#pragma unroll
            for (int ci = 0; ci < 3; ++ci) a0 = fmaf(w0[ci * 9 + ky * 3 + 2], cn[ky * 3 + ci], a0);
        }
#pragma unroll
        for (int ky = 0; ky < 3; ++ky) {
#pragma unroll
            for (int ci = 0; ci < 3; ++ci) a1 = fmaf(w1[ci * 9 + ky * 3 + 0], cm[ky * 3 + ci], a1);
#pragma unroll
            for (int ci = 0; ci < 3; ++ci) a1 = fmaf(w1[ci * 9 + ky * 3 + 1], cc[ky * 3 + ci], a1);
#pragma unroll
            for (int ci = 0; ci < 3; ++ci) a1 = fmaf(w1[ci * 9 + ky * 3 + 2], cn[ky * 3 + ci], a1);
        }
        u64 bits0 = __ballot(bn_neg_s(a0, si0, b0, m0));
        u64 bits1 = __ballot(bn_neg_s(a1, si1, b1, m1));
        if (lane == 0) {
            ulonglong2 st; st.x = bits0; st.y = bits1;
            *(ulonglong2*)(orow + xx * 2) = st;
        }
#pragma unroll
        for (int t = 0; t < 9; ++t) { cm[t] = cc[t]; cc[t] = cn[t]; }
    }
}

// ---------------- binary conv, LDS-staged (XNOR-popcount), fp32 bit-exact epilogue ----------------
// R6: K-chunk path = PAIR granularity (wc[18], ds_read_b128) + fresh per-pixel window loads
// (no cross-pixel sliding, no shift movs). Live set ~105 real VGPR < MINW=4's 128 cap:
// pair+sliding demanded ~160 (spilled, R5); single-word fit but had 2x load/mov overhead (R6).
// VGPR_Count in counter CSV is 2-reg granules. W2==1 path untouched.
template<int WORDS, int COW, bool POOL, bool HAS_BIAS, int H, int YS, int NWAVES, int MINW>
__global__ __launch_bounds__(NWAVES * 64, MINW) void binconv_lds(
    const u64* __restrict__ a, const u64* __restrict__ wb,
    const float* __restrict__ g, const float* __restrict__ bb,
    const float* __restrict__ m, const float* __restrict__ v,
    const float* __restrict__ bias, u64* __restrict__ out, int N)
{
    const int W = H;
    const int OH = POOL ? H / 2 : H, OW = POOL ? W / 2 : W;
    const int COUT = COW * 64;
    const int OROWS = OH / YS;
    const int RMAX = POOL ? OROWS * 2 + 2 : OROWS + 2;
    const int PR = POOL ? 4 : 3;
    const int NW = POOL ? 4 : 1;
    const int W2 = WORDS / 2;
    const int S = POOL ? 2 : 1;          // x stride between outputs
    const int NBC = 9 * WORDS * 64;      // valid bits per subwindow, interior
    const int GPX = (OW <= 4) ? OW : ((NW == 4) ? 4 : OW);   // pixels per acc-group
    const int NG = OW / GPX;

    __shared__ alignas(16) u64 tile[RMAX * W * WORDS];

    int blk = blockIdx.x;
    int ys = blk % YS, n = blk / YS;
    int oy0 = ys * OROWS;
    int iy0 = (POOL ? oy0 * 2 - 1 : oy0 - 1); if (iy0 < 0) iy0 = 0;
    int iy1 = (POOL ? (oy0 + OROWS - 1) * 2 + 2 : oy0 + OROWS); if (iy1 > H - 1) iy1 = H - 1;
    int R = iy1 - iy0 + 1;
    {
        const u64* src = a + ((size_t)(n * H + iy0) * W) * WORDS;
        int tot = R * W * WORDS;
        for (int i = threadIdx.x; i < tot; i += NWAVES * 64) tile[i] = src[i];
    }
    __syncthreads();

    int lane = threadIdx.x & 63;
    int wv = uread((int)(threadIdx.x >> 6));

    int cw0, r0, r1;
    if (COW >= NWAVES) { cw0 = wv; r0 = 0; r1 = OROWS; }
    else { cw0 = wv % COW; int chunk = OROWS * COW / NWAVES; r0 = (wv / COW) * chunk; r1 = r0 + chunk; }

    const ulonglong2* t2 = (const ulonglong2*)tile;

    for (int cw = cw0; cw < COW; cw += NWAVES) {
        int co = cw * 64 + lane;
        float bc = bb[co], mc = m[co];
        float sic = bn_scale(g[co], v[co]);
        float bi = HAS_BIAS ? bias[co] : 0.f;

        auto store_px = [&](int oy, int ox, int best) {
            float tv = (float)best;
            if (HAS_BIAS) tv = fr(tv + bi);
            u64 bits = __ballot(bn_neg_s(tv, sic, bc, mc));
            if (lane == 0) out[((size_t)(n * OH + oy) * OW + ox) * COW + cw] = bits;
        };

        if constexpr (W2 == 1) {
            u64 wgt[18];
#pragma unroll
            for (int t = 0; t < 18; ++t) wgt[t] = wb[(size_t)t * COUT + co];

            // general (border-capable) path — BIT-FROZEN
            auto px_general = [&](int oy, int ox) {
                int y0 = (POOL ? oy * 2 : oy) - 1;
                bool rv[PR];
#pragma unroll
                for (int p = 0; p < PR; ++p) rv[p] = ((unsigned)(y0 + p) < (unsigned)H);
                int x0 = (POOL ? ox * 2 : ox) - 1;
                bool cv[PR];
#pragma unroll
                for (int q = 0; q < PR; ++q) cv[q] = ((unsigned)(x0 + q) < (unsigned)W);

                int acc[NW], nb[NW];
#pragma unroll
                for (int i = 0; i < NW; ++i) { acc[i] = 0; nb[i] = 0; }
#pragma unroll
                for (int sy = 0; sy < (POOL ? 2 : 1); ++sy)
#pragma unroll
                for (int sx = 0; sx < (POOL ? 2 : 1); ++sx)
#pragma unroll
                for (int ky = 0; ky < 3; ++ky)
#pragma unroll
                for (int kx = 0; kx < 3; ++kx)
                    if (rv[sy + ky] && cv[sx + kx]) nb[POOL ? sy * 2 + sx : 0] += WORDS * 64;

                ulonglong2 pt[PR][PR];
#pragma unroll
                for (int p = 0; p < PR; ++p) if (rv[p]) {
                    int lrow = y0 + p - iy0;
#pragma unroll
                    for (int q = 0; q < PR; ++q) if (cv[q])
                        pt[p][q] = t2[(lrow * W + (x0 + q))];
                }
#pragma unroll
                for (int sy = 0; sy < (POOL ? 2 : 1); ++sy)
#pragma unroll
                for (int sx = 0; sx < (POOL ? 2 : 1); ++sx)
#pragma unroll
                for (int ky = 0; ky < 3; ++ky)
#pragma unroll
                for (int kx = 0; kx < 3; ++kx)
                    if (rv[sy + ky] && cv[sx + kx]) {
                        ulonglong2 q = pt[sy + ky][sx + kx];
                        int wi = POOL ? sy * 2 + sx : 0;
                        acc[wi] += __popcll(q.x ^ wgt[(ky * 3 + kx) * 2])
                                 + __popcll(q.y ^ wgt[(ky * 3 + kx) * 2 + 1]);
                    }
                int best = 0;
#pragma unroll
                for (int i = 0; i < NW; ++i) {
                    int dot = nb[i] - 2 * acc[i];
                    best = (i == 0) ? dot : max(best, dot);
                }
                store_px(oy, ox, best);
            };

            for (int oy = oy0 + r0; oy < oy0 + r1; ++oy) {
                int y0 = (POOL ? oy * 2 : oy) - 1;
                if (y0 < 0 || y0 + PR > H) {           // border row: full general path
                    for (int ox = 0; ox < OW; ++ox) px_general(oy, ox);
                    continue;
                }
                int base = y0 - iy0;                   // top tile row of the window (in-tile, valid)
                px_general(oy, 0);
                for (int ox = 1; ox < OW - 1; ++ox) {
                    int x0 = S * ox - 1;
                    int acc[NW];
#pragma unroll
                    for (int i = 0; i < NW; ++i) acc[i] = 0;
                    ulonglong2 win[PR][PR];
#pragma unroll
                    for (int p = 0; p < PR; ++p) {
                        const ulonglong2* rp = t2 + (base + p) * W + x0;
#pragma unroll
                        for (int q = 0; q < PR; ++q) win[p][q] = rp[q];
                    }
#pragma unroll
                    for (int sy = 0; sy < (POOL ? 2 : 1); ++sy)
#pragma unroll
                    for (int sx = 0; sx < (POOL ? 2 : 1); ++sx)
#pragma unroll
                    for (int ky = 0; ky < 3; ++ky)
#pragma unroll
                    for (int kx = 0; kx < 3; ++kx) {
                        ulonglong2 q = win[sy + ky][sx + kx];
                        int wi = POOL ? sy * 2 + sx : 0;
                        acc[wi] += __popcll(q.x ^ wgt[(ky * 3 + kx) * 2])
                                 + __popcll(q.y ^ wgt[(ky * 3 + kx) * 2 + 1]);
                    }
                    int best = 0;
#pragma unroll
                    for (int i = 0; i < NW; ++i) {
                        int dot = NBC - 2 * acc[i];
                        best = (i == 0) ? dot : max(best, dot);
                    }
                    store_px(oy, ox, best);
                }
                px_general(oy, OW - 1);
            }
        } else {
            // ---- K-chunked PAIR path (WORDS >= 4): wc[18] live, fresh b128 window per px ----
            for (int oy = oy0 + r0; oy < oy0 + r1; ++oy) {
                int y0r = (POOL ? oy * 2 : oy) - 1;
                bool rv[PR];
#pragma unroll
                for (int p = 0; p < PR; ++p) rv[p] = ((unsigned)(y0r + p) < (unsigned)H);
                int baseR = y0r - iy0;                 // only used where rv[p] true -> in-tile

#pragma unroll
                for (int gg = 0; gg < NG; ++gg) {
                    int acc[GPX][NW];
#pragma unroll
                    for (int i = 0; i < GPX; ++i)
#pragma unroll
                        for (int wi = 0; wi < NW; ++wi) acc[i][wi] = 0;

#pragma unroll 1
                    for (int w2 = 0; w2 < W2; ++w2) {
                        u64 wc[18];
#pragma unroll
                        for (int t = 0; t < 9; ++t) {
                            wc[t * 2]     = wb[(size_t)(t * WORDS + 2 * w2) * COUT + co];
                            wc[t * 2 + 1] = wb[(size_t)(t * WORDS + 2 * w2 + 1) * COUT + co];
                        }
#pragma unroll
                        for (int i = 0; i < GPX; ++i) {
                            const int ox = gg * GPX + i;
                            const int x0 = S * ox - 1;
                            ulonglong2 pt[PR][PR];
#pragma unroll
                            for (int p = 0; p < PR; ++p) {
                                if (rv[p]) {
#pragma unroll
                                    for (int q = 0; q < PR; ++q) {
                                        const int x = x0 + q;          // compile-time
                                        if (x >= 0 && x < W)
                                            pt[p][q] = t2[((baseR + p) * W + x) * W2 + w2];
                                    }
                                }
                            }
#pragma unroll
                            for (int sy = 0; sy < (POOL ? 2 : 1); ++sy)
#pragma unroll
                            for (int sx = 0; sx < (POOL ? 2 : 1); ++sx)
#pragma unroll
                            for (int ky = 0; ky < 3; ++ky)
#pragma unroll
                            for (int kx = 0; kx < 3; ++kx) {
                                const int xq = x0 + sx + kx;           // compile-time
                                if (xq >= 0 && xq < W) {
                                    if (rv[sy + ky]) {
                                        ulonglong2 q = pt[sy + ky][sx + kx];
                                        const int t = ky * 3 + kx;
                                        const int wi = POOL ? sy * 2 + sx : 0;
                                        acc[i][wi] += __popcll(q.x ^ wc[t * 2])
                                                    + __popcll(q.y ^ wc[t * 2 + 1]);
                                    }
                                }
                            }
                        }
                    }

                    // epilogue: nb from (compile-time cv) x (runtime rv), pooled max, bn sign
#pragma unroll
                    for (int i = 0; i < GPX; ++i) {
                        const int ox = gg * GPX + i;
                        const int x0 = S * ox - 1;
                        int nb[NW];
#pragma unroll
                        for (int wi = 0; wi < NW; ++wi) nb[wi] = 0;
#pragma unroll
                        for (int sy = 0; sy < (POOL ? 2 : 1); ++sy)
#pragma unroll
                        for (int sx = 0; sx < (POOL ? 2 : 1); ++sx)
#pragma unroll
                        for (int ky = 0; ky < 3; ++ky)
#pragma unroll
                        for (int kx = 0; kx < 3; ++kx) {
                            const int xq = x0 + sx + kx;
                            if (xq >= 0 && xq < W) {
                                if (rv[sy + ky]) nb[POOL ? sy * 2 + sx : 0] += WORDS * 64;
                            }
                        }
                        int best = 0;
#pragma unroll
                        for (int wi = 0; wi < NW; ++wi) {
                            int dot = nb[wi] - 2 * acc[i][wi];
                            best = (wi == 0) ? dot : max(best, dot);
                        }
                        store_px(oy, ox, best);
                    }
                }
            }
        }
    }
}

// ---------------- binary FC, fp32 bit-exact epilogue (frozen) ----------------
template<int KW, int OWRD>
__global__ __launch_bounds__(256) void binfc_kernel(
    const u64* __restrict__ a, const u64* __restrict__ wb,
    const float* __restrict__ g, const float* __restrict__ bb,
    const float* __restrict__ m, const float* __restrict__ v,
    u64* __restrict__ out, int N)
{
    int lane = threadIdx.x & 63;
    int wid = uread(blockIdx.x * 4 + (threadIdx.x >> 6));
    if (wid >= N * OWRD) return;
    int ow = wid & (OWRD - 1), n = wid / OWRD;
    int o = ow * 64 + lane;
    const u64* ap = a + (size_t)n * KW;
    int acc = 0;
#pragma unroll 8
    for (int k = 0; k < KW; ++k)
        acc += __popcll(ap[k] ^ wb[(size_t)k * (OWRD * 64) + o]);
    float dotf = (float)(KW * 64 - 2 * acc);
    float si = bn_scale(g[o], v[o]);
    u64 bits = __ballot(bn_neg_s(dotf, si, bb[o], m[o]));
    if (lane == 0) out[(size_t)n * OWRD + ow] = bits;
}

// ---------------- fc9 + bn(affine=False) + log_softmax, fp32 output (frozen) ----------------
__global__ __launch_bounds__(64) void fc9_kernel(
    const u64* __restrict__ a, const u64* __restrict__ wb,
    const float* __restrict__ m, const float* __restrict__ v, float* __restrict__ out)
{
    int n = blockIdx.x, t = threadIdx.x;
    const u64* ap = a + (size_t)n * 16;
    float val = -1e30f;
    if (t < 10) {
        int acc = 0;
#pragma unroll
        for (int k = 0; k < 16; ++k) acc += __popcll(ap[k] ^ wb[k * 16 + t]);
        float dotf = (float)(1024 - 2 * acc);
        float inv = fr(1.0f / fr(sqrtf(fr(v[t] + 1e-5f))));
        float t1  = fr(dotf - m[t]);
        val = fr(t1 * inv);
    }
    float mx = val;
#pragma unroll
    for (int off = 32; off; off >>= 1) mx = fmaxf(mx, __shfl_xor(mx, off));
    float sh = fr(val - mx);
    double e = (t < 10) ? exp((double)sh) : 0.0;
    double sum = e;
#pragma unroll
    for (int off = 32; off; off >>= 1) sum += __shfl_xor(sum, off);
    if (t < 10) out[n * 10 + t] = (float)((double)sh - log(sum));
}

extern "C" void kernel_launch(void* const* d_in, const int* in_sizes, int n_in,
                              void* d_out, int out_size, void* d_ws, size_t ws_size,
                              hipStream_t stream) {
    // setup_inputs() dict order
    auto F = [&](int i) { return (const float*)d_in[i]; };
    const float* x  = F(0);
    const float* w1 = F(1);  const float* g1 = F(2);  const float* b1 = F(3);
    const float* m1 = F(4);  const float* v1 = F(5);
    const float* w2 = F(6);  const float* g2 = F(7);  const float* b2 = F(8);
    const float* m2 = F(9);  const float* v2 = F(10);
    const float* w3 = F(11); const float* g3 = F(12); const float* b3 = F(13);
    const float* m3 = F(14); const float* v3 = F(15);
    const float* w4 = F(16); const float* g4 = F(17); const float* b4 = F(18);
    const float* m4 = F(19); const float* v4 = F(20);
    const float* w5 = F(21); const float* g5 = F(22); const float* b5 = F(23);
    const float* m5 = F(24); const float* v5 = F(25);
    const float* w6 = F(26); const float* g6 = F(27); const float* b6 = F(28);
    const float* m6 = F(29); const float* v6 = F(30);
    const float* bias2 = F(31);
    const float* w7 = F(32); const float* m7 = F(33); const float* v7 = F(34);
    const float* g7 = F(35); const float* b7 = F(36);
    const float* w8 = F(37); const float* m8 = F(38); const float* v8 = F(39);
    const float* g8 = F(40); const float* b8 = F(41);
    const float* w9 = F(42); const float* m9 = F(43); const float* v9 = F(44);
    (void)in_sizes; (void)n_in; (void)ws_size;

    const int N = out_size / 10;
    u64* ws = (u64*)d_ws;
    size_t off = 0;
    auto carve = [&](size_t nwords) { u64* p = ws + off; off += nwords; return p; };
    float* w1s = (float*)carve(1728);
    u64* w2p = carve(2304);
    u64* w3p = carve(4608);
    u64* w4p = carve(9216);
    u64* w5p = carve(18432);
    u64* w6p = carve(36864);
    u64* w7p = carve(131072);
    u64* w8p = carve(16384);
    u64* w9p = carve(256);
    u64* a1 = carve((size_t)N * 32 * 32 * 2);
    u64* a2 = carve((size_t)N * 16 * 16 * 2);
    u64* a3 = carve((size_t)N * 16 * 16 * 4);
    u64* a4 = carve((size_t)N * 8 * 8 * 4);
    u64* a5 = carve((size_t)N * 8 * 8 * 8);
    u64* a6 = carve((size_t)N * 16 * 8);
    u64* f7 = carve((size_t)N * 16);
    u64* f8 = carve((size_t)N * 16);

    pack_all_kernel<<<8182, 256, 0, stream>>>(w1, w1s, w2, w2p, w3, w3p, w4, w4p,
                                              w5, w5p, w6, w6p, w7, w7p, w8, w8p, w9, w9p);

    conv1_kernel<<<(N * 32 + 3) / 4, 256, 0, stream>>>(x, w1s, g1, b1, m1, v1, a1, N);

    // binconv: conv2-5 at YS=8 (8 blocks/CU), conv6 at YS=4 with 8-wave blocks; MINW=4
    binconv_lds<2, 2, true, true, 32, 8, 4, 4><<<N * 8, 256, 0, stream>>>(
        a1, w2p, g2, b2, m2, v2, bias2, a2, N);
    binconv_lds<2, 4, false, false, 16, 8, 4, 4><<<N * 8, 256, 0, stream>>>(
        a2, w3p, g3, b3, m3, v3, nullptr, a3, N);
    binconv_lds<4, 4, true, false, 16, 8, 4, 4><<<N * 8, 256, 0, stream>>>(
        a3, w4p, g4, b4, m4, v4, nullptr, a4, N);
    binconv_lds<4, 8, false, false, 8, 8, 4, 4><<<N * 8, 256, 0, stream>>>(
        a4, w5p, g5, b5, m5, v5, nullptr, a5, N);
    binconv_lds<8, 8, true, false, 8, 4, 8, 4><<<N * 4, 512, 0, stream>>>(
        a5, w6p, g6, b6, m6, v6, nullptr, a6, N);

    binfc_kernel<128, 16><<<(N * 16 + 3) / 4, 256, 0, stream>>>(a6, w7p, g7, b7, m7, v7, f7, N);
    binfc_kernel<16, 16><<<(N * 16 + 3) / 4, 256, 0, stream>>>(f7, w8p, g8, b8, m8, v8, f8, N);

    fc9_kernel<<<N, 64, 0, stream>>>(f8, w9p, m9, v9, (float*)d_out);
}